// Round 15
// baseline (348.910 us; speedup 1.0000x reference)
//
#include <hip/hip_runtime.h>

#define N_NODES   50000
#define N_EDGES   800000
#define HID       64
#define NUM_GRAPHS 50
#define EPS       1e-5f
#define NWT       3125           // 16-node wave-tiles (3125*16 = 50000)
#define NBC       782            // k_combine blocks = ceil(NWT/4)
#define NPX       1563           // prepX blocks = ceil(N*8/256)
#define NHPAD     50176          // 98 * 512, padded histogram/scan size
#define SCAN_B    98
#define NBKT      98             // coarse buckets = dst >> 9 (512 nodes each)
#define BSH       9
#define BATCH     2048           // edges per k_bin block (8 per thread)

typedef __attribute__((ext_vector_type(8))) short short8;
typedef __attribute__((ext_vector_type(4))) float f32x4;

__device__ __forceinline__ unsigned short bfbits(float x) {
    __bf16 h = (__bf16)x;
    return __builtin_bit_cast(unsigned short, h);
}
// 8 fp32 -> 8 bf16 (RTN)
__device__ __forceinline__ short8 cvt8hi(const float4& a, const float4& b) {
    float f[8] = {a.x, a.y, a.z, a.w, b.x, b.y, b.z, b.w};
    short8 hi;
#pragma unroll
    for (int i = 0; i < 8; ++i) hi[i] = (short)bfbits(f[i]);
    return hi;
}

// ---------------------------------------------------------------------------
// Int histogram of dst (degree count).
__global__ __launch_bounds__(256) void k_hist(const int* __restrict__ dst,
                                              int* __restrict__ ihist) {
    int tid = blockIdx.x * blockDim.x + threadIdx.x;
    int stride = gridDim.x * blockDim.x;
    for (int e = tid; e < N_EDGES; e += stride) atomicAdd(&ihist[dst[e]], 1);
}

// Exclusive scan, pass 1: per-block (512 elems) local scan + block sums.
__global__ __launch_bounds__(512) void k_scan1(const int* __restrict__ ihist,
                                               int* __restrict__ off,
                                               int* __restrict__ bsum) {
    __shared__ int s[512];
    const int t = threadIdx.x, i = blockIdx.x * 512 + t;
    const int v = ihist[i];
    s[t] = v;
    __syncthreads();
    for (int o = 1; o < 512; o <<= 1) {
        int u = (t >= o) ? s[t - o] : 0;
        __syncthreads();
        s[t] += u;
        __syncthreads();
    }
    off[i] = s[t] - v;
    if (t == 511) bsum[blockIdx.x] = s[t];
}

// pass 2: serial exclusive scan of the 98 block sums.
__global__ void k_scan2(const int* __restrict__ bsum, int* __restrict__ bscan) {
    if (threadIdx.x == 0) {
        int acc = 0;
        for (int b = 0; b < SCAN_B; ++b) { bscan[b] = acc; acc += bsum[b]; }
    }
}

// pass 3: add block offsets in place; emit bucket cursors at bucket heads.
__global__ __launch_bounds__(512) void k_scan3(int* __restrict__ off,
                                               const int* __restrict__ bscan,
                                               int* __restrict__ bcur) {
    const int i = blockIdx.x * 512 + threadIdx.x;
    const int v = off[i] + bscan[i >> 9];
    off[i] = v;
    if ((i & 511) == 0) bcur[i >> 9] = v;
}

// ---------------------------------------------------------------------------
// Pass 1: bin edges into 98 coarse buckets (dst>>9).
__global__ __launch_bounds__(256) void k_bin(const int* __restrict__ src,
                                             const int* __restrict__ dst,
                                             int* __restrict__ bcur,
                                             int2* __restrict__ binned) {
    __shared__ int bh[NBKT], gb[NBKT];
    const int tid = threadIdx.x;
    const int base = blockIdx.x * BATCH + tid * 8;
    int2 rec[8]; int bk[8]; bool val[8];
#pragma unroll
    for (int j = 0; j < 8; ++j) {
        const int e = base + j;
        val[j] = e < N_EDGES;
        if (val[j]) {
            const int d = dst[e];
            rec[j] = int2{src[e] | (d << 16), e};
            bk[j] = d >> BSH;
        } else bk[j] = 0;
    }
    if (tid < NBKT) bh[tid] = 0;
    __syncthreads();
#pragma unroll
    for (int j = 0; j < 8; ++j) if (val[j]) atomicAdd(&bh[bk[j]], 1);
    __syncthreads();
    if (tid < NBKT) { gb[tid] = atomicAdd(&bcur[tid], bh[tid]); bh[tid] = 0; }
    __syncthreads();
#pragma unroll
    for (int j = 0; j < 8; ++j)
        if (val[j]) {
            const int r = atomicAdd(&bh[bk[j]], 1);
            binned[gb[bk[j]] + r] = rec[j];
        }
}

// ---------------------------------------------------------------------------
// Pass 2: one block per bucket; per-node LDS cursors; XCD-local scatter.
// Outputs: epk (src|dst<<16, 4B) and seid (orig edge id, 4B).
__global__ __launch_bounds__(256) void k_sortb(const int2* __restrict__ binned,
                                               const int* __restrict__ off,
                                               int* __restrict__ epk,
                                               int* __restrict__ seid) {
    __shared__ int cur[512];
    const int b = blockIdx.x;
    const int nbase = b << BSH;
    const int tid = threadIdx.x;
    for (int i = tid; i < 512; i += 256) cur[i] = off[nbase + i];
    const int start = off[nbase];
    const int end = (b == NBKT - 1) ? N_EDGES : off[nbase + 512];
    __syncthreads();
    for (int p = start + tid; p < end; p += 256) {
        const int2 r = binned[p];
        const int d = ((unsigned)r.x) >> 16;
        const int pos = atomicAdd(&cur[d - nbase], 1);
        epk[pos] = r.x;
        seid[pos] = r.y;
    }
}

// ---------------------------------------------------------------------------
// ea gather-convert into SORTED order: eaS[p] = bf16(ea[seid[p]]).
__global__ __launch_bounds__(256) void k_prepEAS(const float* __restrict__ ea,
                                                 const int* __restrict__ seid,
                                                 unsigned short* __restrict__ eaS) {
    int t = blockIdx.x * blockDim.x + threadIdx.x;
    if (t >= N_EDGES * 4) return;
    const int p = t >> 2, q = t & 3;
    const int eid = seid[p];
    float4 a = *(const float4*)(ea + (size_t)eid * 32 + q * 8);
    float4 b = *(const float4*)(ea + (size_t)eid * 32 + q * 8 + 4);
    *(short8*)(eaS + (size_t)p * 32 + q * 8) = cvt8hi(a, b);
}

// ---------------------------------------------------------------------------
// Fused small prep: blocks [0,NPX) convert x -> bf16; last block does
// gcnt (binary search) + all four weight transposes.
__global__ __launch_bounds__(256) void k_prep(const float* __restrict__ x,
                                              unsigned short* __restrict__ xb,
                                              const int* __restrict__ batch,
                                              float* __restrict__ gcnt,
                                              const float* __restrict__ Wn1,
                                              const float* __restrict__ Wn2,
                                              unsigned short* __restrict__ Wb1,
                                              unsigned short* __restrict__ Wb2,
                                              const float* __restrict__ Wr1,
                                              const float* __restrict__ Wr2,
                                              unsigned short* __restrict__ Wrb1,
                                              unsigned short* __restrict__ Wrb2) {
    const int tid = threadIdx.x;
    if (blockIdx.x < NPX) {
        int t = blockIdx.x * 256 + tid;
        if (t >= N_NODES * 8) return;
        float4 a = ((const float4*)(x + (size_t)t * 8))[0];
        float4 b = ((const float4*)(x + (size_t)t * 8))[1];
        *(short8*)(xb + (size_t)t * 8) = cvt8hi(a, b);
        return;
    }
    // tail block
    if (tid < NUM_GRAPHS) {
        auto lb = [&](int val) {
            int lo = 0, hi = N_NODES;
            while (lo < hi) { int mid = (lo + hi) >> 1; if (batch[mid] < val) lo = mid + 1; else hi = mid; }
            return lo;
        };
        gcnt[tid] = (float)(lb(tid + 1) - lb(tid));
    }
    for (int t = tid; t < 96 * 64; t += 256) {
        int k = t >> 6, n = t & 63;
        Wb1[n * 104 + k] = bfbits(Wn1[t]);
        Wb2[n * 104 + k] = bfbits(Wn2[t]);
    }
    for (int t = tid; t < 64 * 64; t += 256) {
        int k = t >> 6, n = t & 63;
        Wrb1[n * 64 + k] = bfbits(Wr1[t]);
        Wrb2[n * 64 + k] = bfbits(Wr2[t]);
    }
}

// ---------------------------------------------------------------------------
// BN-apply (layer1) -> bf16 only.
__global__ __launch_bounds__(256) void k_prepH(const float* __restrict__ h,
                                               const float* __restrict__ ss,
                                               unsigned short* __restrict__ hb) {
    int t = blockIdx.x * blockDim.x + threadIdx.x;
    if (t >= N_NODES * 8) return;
    const int f0 = (t & 7) * 8;
    float4 sca = *(const float4*)(ss + f0);
    float4 scb = *(const float4*)(ss + f0 + 4);
    float4 sha = *(const float4*)(ss + 64 + f0);
    float4 shb = *(const float4*)(ss + 64 + f0 + 4);
    const float* r = h + (size_t)t * 8;
    float4 a = ((const float4*)r)[0];
    float4 b = ((const float4*)r)[1];
    a.x = fmaxf(a.x * sca.x + sha.x, 0.f);
    a.y = fmaxf(a.y * sca.y + sha.y, 0.f);
    a.z = fmaxf(a.z * sca.z + sha.z, 0.f);
    a.w = fmaxf(a.w * sca.w + sha.w, 0.f);
    b.x = fmaxf(b.x * scb.x + shb.x, 0.f);
    b.y = fmaxf(b.y * scb.y + shb.y, 0.f);
    b.z = fmaxf(b.z * scb.z + shb.z, 0.f);
    b.w = fmaxf(b.w * scb.w + shb.w, 0.f);
    *(short8*)(hb + (size_t)t * 8) = cvt8hi(a, b);
}

// ---------------------------------------------------------------------------
// Edge message via MFMA, pure bf16. FOUR 16-edge tiles per wave (64 edges):
// all 12 A-gathers issued up-front (deep MLP), B-frags amortized over 4
// tiles. Register segment reduce + run atomics per tile.
__global__ __launch_bounds__(256) void k_edge(const unsigned short* __restrict__ xb,
                                              const unsigned short* __restrict__ eaS,
                                              const int* __restrict__ epk,
                                              const unsigned short* __restrict__ Wb,
                                              const float* __restrict__ bias,
                                              float* __restrict__ aggr) {
    __shared__ int ldstw[4][4][16];

    const int tid  = threadIdx.x;
    const int lane = tid & 63;
    const int w    = tid >> 6;
    const int ew   = (blockIdx.x * 4 + w) * 64;   // wave's 64 edges (4 tiles)

    const int fr   = lane & 15;
    const int hi4  = lane >> 4;
    const int koff = hi4 * 8;
    const int rb   = hi4 * 4;

    // all 64 dst ids: one per lane
    ldstw[w][lane >> 4][lane & 15] = ((unsigned)epk[ew + lane]) >> 16;

    int sd[4];
#pragma unroll
    for (int t = 0; t < 4; ++t) sd[t] = epk[ew + t * 16 + fr] & 0xffff;

    // A fragments: 8 random x gathers + 4 sequential eaS loads, all in flight
    short8 ax0[4], ax1[4], ae[4];
#pragma unroll
    for (int t = 0; t < 4; ++t) {
        ax0[t] = *(const short8*)(xb + (size_t)sd[t] * 64 + koff);
        ax1[t] = *(const short8*)(xb + (size_t)sd[t] * 64 + 32 + koff);
        ae[t]  = *(const short8*)(eaS + (size_t)(ew + t * 16 + fr) * 32 + koff);
    }

    f32x4 acc[4][4];
#pragma unroll
    for (int nn = 0; nn < 4; ++nn) {
        const float bv = bias[nn * 16 + fr];
#pragma unroll
        for (int t = 0; t < 4; ++t) acc[t][nn] = f32x4{bv, bv, bv, bv};
    }

#pragma unroll
    for (int kb = 0; kb < 3; ++kb) {
#pragma unroll
        for (int nn = 0; nn < 4; ++nn) {
            const short8 bh = *(const short8*)(Wb + (nn * 16 + fr) * 104 + kb * 32 + koff);
#pragma unroll
            for (int t = 0; t < 4; ++t) {
                const short8 a = (kb == 0) ? ax0[t] : (kb == 1) ? ax1[t] : ae[t];
                acc[t][nn] = __builtin_amdgcn_mfma_f32_16x16x32_bf16(a, bh, acc[t][nn], 0, 0, 0);
            }
        }
    }

    // ReLU in place
#pragma unroll
    for (int t = 0; t < 4; ++t)
#pragma unroll
        for (int nn = 0; nn < 4; ++nn)
#pragma unroll
            for (int j = 0; j < 4; ++j) acc[t][nn][j] = fmaxf(acc[t][nn][j], 0.f);

    // register segment-reduce per tile (lane holds rows rb..rb+3 of col nn*16+fr)
#pragma unroll
    for (int t = 0; t < 4; ++t) {
        int r = 0;
        while (r < 16) {
            const int d = ldstw[w][t][r];
            int e2 = r + 1;
            while (e2 < 16 && ldstw[w][t][e2] == d) ++e2;
            float v0 = 0.f, v1 = 0.f, v2 = 0.f, v3 = 0.f;
#pragma unroll
            for (int j = 0; j < 4; ++j) {
                const bool in = (rb + j >= r) && (rb + j < e2);
                v0 += in ? acc[t][0][j] : 0.f;
                v1 += in ? acc[t][1][j] : 0.f;
                v2 += in ? acc[t][2][j] : 0.f;
                v3 += in ? acc[t][3][j] : 0.f;
            }
            v0 += __shfl_xor(v0, 16); v0 += __shfl_xor(v0, 32);
            v1 += __shfl_xor(v1, 16); v1 += __shfl_xor(v1, 32);
            v2 += __shfl_xor(v2, 16); v2 += __shfl_xor(v2, 32);
            v3 += __shfl_xor(v3, 16); v3 += __shfl_xor(v3, 32);
            const float val = hi4 == 0 ? v0 : hi4 == 1 ? v1 : hi4 == 2 ? v2 : v3;
            unsafeAtomicAdd(&aggr[(size_t)d * 64 + lane], val);
            r = e2;
        }
    }
}

// ---------------------------------------------------------------------------
// MFMA combine: h = xin_b16 @ Wr + aggr/deg; zeroes aggr behind the read;
// BN partials.
__global__ __launch_bounds__(256) void k_combine(const unsigned short* __restrict__ xbin,
                                                 const unsigned short* __restrict__ Wrb,
                                                 float* __restrict__ aggr,
                                                 const int*   __restrict__ ihist,
                                                 float* __restrict__ h,
                                                 float* __restrict__ partial) {
    __shared__ float ssum[4][64];
    __shared__ float ssq[4][64];

    const int tid  = threadIdx.x;
    const int lane = tid & 63;
    const int w    = tid >> 6;
    const int wt   = blockIdx.x * 4 + w;
    const int fr   = lane & 15;
    const int hi4  = lane >> 4;
    const int koff = hi4 * 8;
    const int rb   = hi4 * 4;

    float rs[4] = {0.f, 0.f, 0.f, 0.f};
    float rq[4] = {0.f, 0.f, 0.f, 0.f};

    if (wt < NWT) {
        const int n0 = wt * 16;
        const short8 a0 = *(const short8*)(xbin + (size_t)(n0 + fr) * 64 + koff);
        const short8 a1 = *(const short8*)(xbin + (size_t)(n0 + fr) * 64 + 32 + koff);
        f32x4 acc[4] = {};
#pragma unroll
        for (int kb = 0; kb < 2; ++kb) {
            const short8 a = kb == 0 ? a0 : a1;
#pragma unroll
            for (int nn = 0; nn < 4; ++nn) {
                const short8 bh = *(const short8*)(Wrb + (nn * 16 + fr) * 64 + kb * 32 + koff);
                acc[nn] = __builtin_amdgcn_mfma_f32_16x16x32_bf16(a, bh, acc[nn], 0, 0, 0);
            }
        }
        const int4 degs = *(const int4*)(ihist + n0 + rb);
#pragma unroll
        for (int j = 0; j < 4; ++j) {
            const int dg = (&degs.x)[j];
            const float invc = 1.0f / fmaxf((float)dg, 1.0f);
            const int row = n0 + rb + j;
#pragma unroll
            for (int nn = 0; nn < 4; ++nn) {
                const size_t ai = (size_t)row * 64 + nn * 16 + fr;
                const float av = aggr[ai];
                aggr[ai] = 0.f;                       // ready for next layer
                const float v = acc[nn][j] + av * invc;
                h[ai] = v;
                rs[nn] += v;
                rq[nn] += v * v;
            }
        }
    }

#pragma unroll
    for (int nn = 0; nn < 4; ++nn) {
        rs[nn] += __shfl_xor(rs[nn], 16); rs[nn] += __shfl_xor(rs[nn], 32);
        rq[nn] += __shfl_xor(rq[nn], 16); rq[nn] += __shfl_xor(rq[nn], 32);
    }
    if (hi4 == 0) {
#pragma unroll
        for (int nn = 0; nn < 4; ++nn) {
            ssum[w][nn * 16 + fr] = rs[nn];
            ssq[w][nn * 16 + fr]  = rq[nn];
        }
    }
    __syncthreads();
    if (tid < 64) {
        partial[blockIdx.x * 128 + tid] =
            ssum[0][tid] + ssum[1][tid] + ssum[2][tid] + ssum[3][tid];
    } else if (tid < 128) {
        int l = tid - 64;
        partial[blockIdx.x * 128 + 64 + l] =
            ssq[0][l] + ssq[1][l] + ssq[2][l] + ssq[3][l];
    }
}

// ---------------------------------------------------------------------------
__global__ void k_bnfin(const float* __restrict__ partial, const float* __restrict__ g,
                        const float* __restrict__ be, float* __restrict__ ss) {
    __shared__ float tot[128];
    int t = threadIdx.x;
    float s = 0.f;
    for (int b = 0; b < NBC; ++b) s += partial[b * 128 + t];
    tot[t] = s;
    __syncthreads();
    if (t < 64) {
        float mu  = tot[t] * (1.0f / (float)N_NODES);
        float var = tot[64 + t] * (1.0f / (float)N_NODES) - mu * mu;
        float sc  = g[t] * rsqrtf(var + EPS);
        ss[t]      = sc;
        ss[64 + t] = be[t] - mu * sc;
    }
}

// ---------------------------------------------------------------------------
// Fused BN-apply (layer2) + global mean pool partial sums (sorted-run atomics).
__global__ __launch_bounds__(256) void k_bnpool(const float* __restrict__ h,
                                                const float* __restrict__ ss,
                                                const int* __restrict__ batch,
                                                float* __restrict__ gsum) {
    const int lane = threadIdx.x & 63;
    const int wid  = (blockIdx.x * blockDim.x + threadIdx.x) >> 6;
    const int nw   = (gridDim.x * blockDim.x) >> 6;
    const float sc = ss[lane];
    const float sh = ss[64 + lane];
    const int chunk = (N_NODES + nw - 1) / nw;
    const int n0 = wid * chunk;
    const int n1 = min(n0 + chunk, N_NODES);
    int curg = -1;
    float acc = 0.f;
    for (int n = n0; n < n1; ++n) {
        int g = __builtin_amdgcn_readfirstlane(batch[n]);
        if (g != curg) {
            if (curg >= 0) unsafeAtomicAdd(&gsum[curg * 64 + lane], acc);
            curg = g;
            acc = 0.f;
        }
        acc += fmaxf(h[(size_t)n * 64 + lane] * sc + sh, 0.f);
    }
    if (curg >= 0) unsafeAtomicAdd(&gsum[curg * 64 + lane], acc);
}

// ---------------------------------------------------------------------------
__global__ void k_final(const float* __restrict__ gsum, const float* __restrict__ gcnt,
                        const float* __restrict__ Wro, const float* __restrict__ bro,
                        float* __restrict__ out) {
    int g = blockIdx.x;
    int lane = threadIdx.x;
    float v = gsum[g * 64 + lane] / fmaxf(gcnt[g], 1.0f) * Wro[lane];
#pragma unroll
    for (int off = 32; off > 0; off >>= 1) v += __shfl_down(v, off, 64);
    if (lane == 0) out[g] = v + bro[0];
}

// ---------------------------------------------------------------------------
extern "C" void kernel_launch(void* const* d_in, const int* in_sizes, int n_in,
                              void* d_out, int out_size, void* d_ws, size_t ws_size,
                              hipStream_t stream) {
    (void)in_sizes; (void)n_in; (void)out_size; (void)ws_size;
    const float* x    = (const float*)d_in[0];
    const int*   ei   = (const int*)d_in[1];   // [2, E]
    const float* ea   = (const float*)d_in[2];
    const int*   batch= (const int*)d_in[3];
    const float* Wn1  = (const float*)d_in[4];
    const float* bn1  = (const float*)d_in[5];
    const float* Wr1  = (const float*)d_in[6];
    const float* g1   = (const float*)d_in[7];
    const float* be1  = (const float*)d_in[8];
    const float* Wn2  = (const float*)d_in[9];
    const float* bn2  = (const float*)d_in[10];
    const float* Wr2  = (const float*)d_in[11];
    const float* g2   = (const float*)d_in[12];
    const float* be2  = (const float*)d_in[13];
    const float* Wro  = (const float*)d_in[14];
    const float* bro  = (const float*)d_in[15];
    const int* src = ei;
    const int* dst = ei + N_EDGES;

    float* ws = (float*)d_ws;
    // ---- zeroed region: [gsum | aggr | ihist] ----
    float* gsum   = ws;                               // 3200
    float* aggr   = gsum + 3200;                      // N*64
    int*   ihist  = (int*)(aggr + (size_t)N_NODES * 64); // NHPAD
    const size_t zero_floats = 3200 + (size_t)N_NODES * 64 + NHPAD;
    // ---- non-zeroed ----
    float* h      = (float*)(ihist + NHPAD);          // N*64
    float* gcnt   = h + (size_t)N_NODES * 64;         // 64
    float* part1  = gcnt + 64;                        // NBC*128
    float* part2  = part1 + NBC * 128;                // NBC*128
    float* ss1    = part2 + NBC * 128;                // 128
    float* ss2    = ss1 + 128;                        // 128
    unsigned short* Wb1  = (unsigned short*)(ss2 + 128); // 64*104
    unsigned short* Wb2  = Wb1 + 6656;
    unsigned short* Wrb1 = Wb2 + 6656;                // 64*64
    unsigned short* Wrb2 = Wrb1 + 4096;
    int* off     = (int*)(Wrb2 + 4096);               // NHPAD
    int* bsum    = off + NHPAD;                       // 128
    int* bscan   = bsum + 128;                        // 128
    int* bcur    = bscan + 128;                       // 128
    int2* binned = (int2*)(bcur + 128);               // E int2
    int* epk     = (int*)(binned + N_EDGES);          // E int
    int* seid    = epk + N_EDGES;                     // E int
    unsigned short* xb  = (unsigned short*)(seid + N_EDGES);   // N*64
    unsigned short* hb  = xb + (size_t)N_NODES * 64;           // N*64
    unsigned short* eaS = hb + (size_t)N_NODES * 64;           // E*32

    hipMemsetAsync(d_ws, 0, zero_floats * sizeof(float), stream);

    // ---- edge sort by dst: histogram, scan, two-level bin+sort ----
    k_hist<<<512, 256, 0, stream>>>(dst, ihist);
    k_scan1<<<SCAN_B, 512, 0, stream>>>(ihist, off, bsum);
    k_scan2<<<1, 64, 0, stream>>>(bsum, bscan);
    k_scan3<<<SCAN_B, 512, 0, stream>>>(off, bscan, bcur);
    k_bin<<<(N_EDGES + BATCH - 1) / BATCH, 256, 0, stream>>>(src, dst, bcur, binned);
    k_sortb<<<NBKT, 256, 0, stream>>>(binned, off, epk, seid);
    k_prepEAS<<<N_EDGES * 4 / 256, 256, 0, stream>>>(ea, seid, eaS);

    k_prep<<<NPX + 1, 256, 0, stream>>>(x, xb, batch, gcnt,
                                        Wn1, Wn2, Wb1, Wb2, Wr1, Wr2, Wrb1, Wrb2);

    // ---- layer 1 ----
    k_edge<<<N_EDGES / 256, 256, 0, stream>>>(xb, eaS, epk, Wb1, bn1, aggr);
    k_combine<<<NBC, 256, 0, stream>>>(xb, Wrb1, aggr, ihist, h, part1);
    k_bnfin<<<1, 128, 0, stream>>>(part1, g1, be1, ss1);
    k_prepH<<<(N_NODES * 8 + 255) / 256, 256, 0, stream>>>(h, ss1, hb);

    // ---- layer 2 ----
    k_edge<<<N_EDGES / 256, 256, 0, stream>>>(hb, eaS, epk, Wb2, bn2, aggr);
    k_combine<<<NBC, 256, 0, stream>>>(hb, Wrb2, aggr, ihist, h, part2);
    k_bnfin<<<1, 128, 0, stream>>>(part2, g2, be2, ss2);

    // ---- readout (BN-apply fused into pool) ----
    k_bnpool<<<256, 256, 0, stream>>>(h, ss2, batch, gsum);
    k_final<<<NUM_GRAPHS, 64, 0, stream>>>(gsum, gcnt, Wro, bro, (float*)d_out);
}

// Round 16
// 316.776 us; speedup vs baseline: 1.1014x; 1.1014x over previous
//
#include <hip/hip_runtime.h>

#define N_NODES   50000
#define N_EDGES   800000
#define HID       64
#define NUM_GRAPHS 50
#define EPS       1e-5f
#define NWT       3125           // 16-node wave-tiles (3125*16 = 50000)
#define NBC       782            // k_combine blocks = ceil(NWT/4)
#define NPX       1563           // prepX blocks = ceil(N*8/256)
#define NHPAD     50176          // 98 * 512, padded histogram/scan size
#define SCAN_B    98
#define NBKT      98             // coarse buckets = dst >> 9 (512 nodes each)
#define BSH       9
#define BATCH     2048           // edges per k_bin block (8 per thread)

typedef __attribute__((ext_vector_type(8))) short short8;
typedef __attribute__((ext_vector_type(4))) float f32x4;

__device__ __forceinline__ unsigned short bfbits(float x) {
    __bf16 h = (__bf16)x;
    return __builtin_bit_cast(unsigned short, h);
}
// 8 fp32 -> 8 bf16 (RTN)
__device__ __forceinline__ short8 cvt8hi(const float4& a, const float4& b) {
    float f[8] = {a.x, a.y, a.z, a.w, b.x, b.y, b.z, b.w};
    short8 hi;
#pragma unroll
    for (int i = 0; i < 8; ++i) hi[i] = (short)bfbits(f[i]);
    return hi;
}

// ---------------------------------------------------------------------------
// Int histogram of dst (degree count).
__global__ __launch_bounds__(256) void k_hist(const int* __restrict__ dst,
                                              int* __restrict__ ihist) {
    int tid = blockIdx.x * blockDim.x + threadIdx.x;
    int stride = gridDim.x * blockDim.x;
    for (int e = tid; e < N_EDGES; e += stride) atomicAdd(&ihist[dst[e]], 1);
}

// Exclusive scan, pass 1: per-block (512 elems) local scan + block sums.
__global__ __launch_bounds__(512) void k_scan1(const int* __restrict__ ihist,
                                               int* __restrict__ off,
                                               int* __restrict__ bsum) {
    __shared__ int s[512];
    const int t = threadIdx.x, i = blockIdx.x * 512 + t;
    const int v = ihist[i];
    s[t] = v;
    __syncthreads();
    for (int o = 1; o < 512; o <<= 1) {
        int u = (t >= o) ? s[t - o] : 0;
        __syncthreads();
        s[t] += u;
        __syncthreads();
    }
    off[i] = s[t] - v;
    if (t == 511) bsum[blockIdx.x] = s[t];
}

// pass 2: serial exclusive scan of the 98 block sums.
__global__ void k_scan2(const int* __restrict__ bsum, int* __restrict__ bscan) {
    if (threadIdx.x == 0) {
        int acc = 0;
        for (int b = 0; b < SCAN_B; ++b) { bscan[b] = acc; acc += bsum[b]; }
    }
}

// pass 3: add block offsets in place; emit bucket cursors at bucket heads.
__global__ __launch_bounds__(512) void k_scan3(int* __restrict__ off,
                                               const int* __restrict__ bscan,
                                               int* __restrict__ bcur) {
    const int i = blockIdx.x * 512 + threadIdx.x;
    const int v = off[i] + bscan[i >> 9];
    off[i] = v;
    if ((i & 511) == 0) bcur[i >> 9] = v;
}

// ---------------------------------------------------------------------------
// Pass 1: bin edges into 98 coarse buckets (dst>>9).
__global__ __launch_bounds__(256) void k_bin(const int* __restrict__ src,
                                             const int* __restrict__ dst,
                                             int* __restrict__ bcur,
                                             int2* __restrict__ binned) {
    __shared__ int bh[NBKT], gb[NBKT];
    const int tid = threadIdx.x;
    const int base = blockIdx.x * BATCH + tid * 8;
    int2 rec[8]; int bk[8]; bool val[8];
#pragma unroll
    for (int j = 0; j < 8; ++j) {
        const int e = base + j;
        val[j] = e < N_EDGES;
        if (val[j]) {
            const int d = dst[e];
            rec[j] = int2{src[e] | (d << 16), e};
            bk[j] = d >> BSH;
        } else bk[j] = 0;
    }
    if (tid < NBKT) bh[tid] = 0;
    __syncthreads();
#pragma unroll
    for (int j = 0; j < 8; ++j) if (val[j]) atomicAdd(&bh[bk[j]], 1);
    __syncthreads();
    if (tid < NBKT) { gb[tid] = atomicAdd(&bcur[tid], bh[tid]); bh[tid] = 0; }
    __syncthreads();
#pragma unroll
    for (int j = 0; j < 8; ++j)
        if (val[j]) {
            const int r = atomicAdd(&bh[bk[j]], 1);
            binned[gb[bk[j]] + r] = rec[j];
        }
}

// ---------------------------------------------------------------------------
// Pass 2: one block per bucket; per-node LDS cursors; XCD-local scatter.
// Outputs: epk (src|dst<<16, 4B) and seid (orig edge id, 4B).
__global__ __launch_bounds__(256) void k_sortb(const int2* __restrict__ binned,
                                               const int* __restrict__ off,
                                               int* __restrict__ epk,
                                               int* __restrict__ seid) {
    __shared__ int cur[512];
    const int b = blockIdx.x;
    const int nbase = b << BSH;
    const int tid = threadIdx.x;
    for (int i = tid; i < 512; i += 256) cur[i] = off[nbase + i];
    const int start = off[nbase];
    const int end = (b == NBKT - 1) ? N_EDGES : off[nbase + 512];
    __syncthreads();
    for (int p = start + tid; p < end; p += 256) {
        const int2 r = binned[p];
        const int d = ((unsigned)r.x) >> 16;
        const int pos = atomicAdd(&cur[d - nbase], 1);
        epk[pos] = r.x;
        seid[pos] = r.y;
    }
}

// ---------------------------------------------------------------------------
// ea gather-convert into SORTED order: eaS[p] = bf16(ea[seid[p]]).
__global__ __launch_bounds__(256) void k_prepEAS(const float* __restrict__ ea,
                                                 const int* __restrict__ seid,
                                                 unsigned short* __restrict__ eaS) {
    int t = blockIdx.x * blockDim.x + threadIdx.x;
    if (t >= N_EDGES * 4) return;
    const int p = t >> 2, q = t & 3;
    const int eid = seid[p];
    float4 a = *(const float4*)(ea + (size_t)eid * 32 + q * 8);
    float4 b = *(const float4*)(ea + (size_t)eid * 32 + q * 8 + 4);
    *(short8*)(eaS + (size_t)p * 32 + q * 8) = cvt8hi(a, b);
}

// ---------------------------------------------------------------------------
// Fused small prep: blocks [0,NPX) convert x -> bf16; last block does
// gcnt (binary search) + all four weight transposes.
__global__ __launch_bounds__(256) void k_prep(const float* __restrict__ x,
                                              unsigned short* __restrict__ xb,
                                              const int* __restrict__ batch,
                                              float* __restrict__ gcnt,
                                              const float* __restrict__ Wn1,
                                              const float* __restrict__ Wn2,
                                              unsigned short* __restrict__ Wb1,
                                              unsigned short* __restrict__ Wb2,
                                              const float* __restrict__ Wr1,
                                              const float* __restrict__ Wr2,
                                              unsigned short* __restrict__ Wrb1,
                                              unsigned short* __restrict__ Wrb2) {
    const int tid = threadIdx.x;
    if (blockIdx.x < NPX) {
        int t = blockIdx.x * 256 + tid;
        if (t >= N_NODES * 8) return;
        float4 a = ((const float4*)(x + (size_t)t * 8))[0];
        float4 b = ((const float4*)(x + (size_t)t * 8))[1];
        *(short8*)(xb + (size_t)t * 8) = cvt8hi(a, b);
        return;
    }
    // tail block
    if (tid < NUM_GRAPHS) {
        auto lb = [&](int val) {
            int lo = 0, hi = N_NODES;
            while (lo < hi) { int mid = (lo + hi) >> 1; if (batch[mid] < val) lo = mid + 1; else hi = mid; }
            return lo;
        };
        gcnt[tid] = (float)(lb(tid + 1) - lb(tid));
    }
    for (int t = tid; t < 96 * 64; t += 256) {
        int k = t >> 6, n = t & 63;
        Wb1[n * 104 + k] = bfbits(Wn1[t]);
        Wb2[n * 104 + k] = bfbits(Wn2[t]);
    }
    for (int t = tid; t < 64 * 64; t += 256) {
        int k = t >> 6, n = t & 63;
        Wrb1[n * 64 + k] = bfbits(Wr1[t]);
        Wrb2[n * 64 + k] = bfbits(Wr2[t]);
    }
}

// ---------------------------------------------------------------------------
// BN-apply (layer1) -> bf16 only.
__global__ __launch_bounds__(256) void k_prepH(const float* __restrict__ h,
                                               const float* __restrict__ ss,
                                               unsigned short* __restrict__ hb) {
    int t = blockIdx.x * blockDim.x + threadIdx.x;
    if (t >= N_NODES * 8) return;
    const int f0 = (t & 7) * 8;
    float4 sca = *(const float4*)(ss + f0);
    float4 scb = *(const float4*)(ss + f0 + 4);
    float4 sha = *(const float4*)(ss + 64 + f0);
    float4 shb = *(const float4*)(ss + 64 + f0 + 4);
    const float* r = h + (size_t)t * 8;
    float4 a = ((const float4*)r)[0];
    float4 b = ((const float4*)r)[1];
    a.x = fmaxf(a.x * sca.x + sha.x, 0.f);
    a.y = fmaxf(a.y * sca.y + sha.y, 0.f);
    a.z = fmaxf(a.z * sca.z + sha.z, 0.f);
    a.w = fmaxf(a.w * sca.w + sha.w, 0.f);
    b.x = fmaxf(b.x * scb.x + shb.x, 0.f);
    b.y = fmaxf(b.y * scb.y + shb.y, 0.f);
    b.z = fmaxf(b.z * scb.z + shb.z, 0.f);
    b.w = fmaxf(b.w * scb.w + shb.w, 0.f);
    *(short8*)(hb + (size_t)t * 8) = cvt8hi(a, b);
}

// ---------------------------------------------------------------------------
// Edge message via MFMA, pure bf16. 2 tiles/wave (measured ILP optimum);
// epk is 4B (src|dst<<16); ea read sequentially from sorted eaS.
// Register segment reduce + run atomics per tile.
__global__ __launch_bounds__(256) void k_edge(const unsigned short* __restrict__ xb,
                                              const unsigned short* __restrict__ eaS,
                                              const int* __restrict__ epk,
                                              const unsigned short* __restrict__ Wb,
                                              const float* __restrict__ bias,
                                              float* __restrict__ aggr) {
    __shared__ int ldstw[4][2][16];

    const int tid  = threadIdx.x;
    const int lane = tid & 63;
    const int w    = tid >> 6;
    const int ew   = (blockIdx.x * 4 + w) * 32;

    const int fr   = lane & 15;
    const int hi4  = lane >> 4;
    const int koff = hi4 * 8;
    const int rb   = hi4 * 4;

    if (lane < 32)
        ldstw[w][lane >> 4][lane & 15] = ((unsigned)epk[ew + lane]) >> 16;

    const int sdA = epk[ew + fr];
    const int sdB = epk[ew + 16 + fr];
    const int sA = sdA & 0xffff;
    const int sB = sdB & 0xffff;

    // A fragments: x gathered (random), ea streamed (sorted rows)
    short8 aA0 = *(const short8*)(xb + (size_t)sA * 64 + koff);
    short8 aA1 = *(const short8*)(xb + (size_t)sA * 64 + 32 + koff);
    short8 aA2 = *(const short8*)(eaS + (size_t)(ew + fr) * 32 + koff);
    short8 aB0 = *(const short8*)(xb + (size_t)sB * 64 + koff);
    short8 aB1 = *(const short8*)(xb + (size_t)sB * 64 + 32 + koff);
    short8 aB2 = *(const short8*)(eaS + (size_t)(ew + 16 + fr) * 32 + koff);

    f32x4 accA[4], accB[4];
#pragma unroll
    for (int n = 0; n < 4; ++n) {
        const float bv = bias[n * 16 + fr];
        accA[n] = f32x4{bv, bv, bv, bv};
        accB[n] = f32x4{bv, bv, bv, bv};
    }

#pragma unroll
    for (int kb = 0; kb < 3; ++kb) {
        const short8 aA = (kb == 0) ? aA0 : (kb == 1) ? aA1 : aA2;
        const short8 aB = (kb == 0) ? aB0 : (kb == 1) ? aB1 : aB2;
#pragma unroll
        for (int nn = 0; nn < 4; ++nn) {
            const short8 bh = *(const short8*)(Wb + (nn * 16 + fr) * 104 + kb * 32 + koff);
            accA[nn] = __builtin_amdgcn_mfma_f32_16x16x32_bf16(aA, bh, accA[nn], 0, 0, 0);
            accB[nn] = __builtin_amdgcn_mfma_f32_16x16x32_bf16(aB, bh, accB[nn], 0, 0, 0);
        }
    }

    // ReLU in place
#pragma unroll
    for (int n = 0; n < 4; ++n)
#pragma unroll
        for (int j = 0; j < 4; ++j) {
            accA[n][j] = fmaxf(accA[n][j], 0.f);
            accB[n][j] = fmaxf(accB[n][j], 0.f);
        }

    // register segment-reduce per tile (lane holds rows rb..rb+3 of col n*16+fr)
#define SEGREDUCE(TT, ACC)                                                    \
    {                                                                         \
        int r = 0;                                                            \
        while (r < 16) {                                                      \
            const int d = ldstw[w][TT][r];                                    \
            int e2 = r + 1;                                                   \
            while (e2 < 16 && ldstw[w][TT][e2] == d) ++e2;                    \
            float v0 = 0.f, v1 = 0.f, v2 = 0.f, v3 = 0.f;                     \
            _Pragma("unroll")                                                 \
            for (int j = 0; j < 4; ++j) {                                     \
                const bool in = (rb + j >= r) && (rb + j < e2);               \
                v0 += in ? ACC[0][j] : 0.f;                                   \
                v1 += in ? ACC[1][j] : 0.f;                                   \
                v2 += in ? ACC[2][j] : 0.f;                                   \
                v3 += in ? ACC[3][j] : 0.f;                                   \
            }                                                                 \
            v0 += __shfl_xor(v0, 16); v0 += __shfl_xor(v0, 32);               \
            v1 += __shfl_xor(v1, 16); v1 += __shfl_xor(v1, 32);               \
            v2 += __shfl_xor(v2, 16); v2 += __shfl_xor(v2, 32);               \
            v3 += __shfl_xor(v3, 16); v3 += __shfl_xor(v3, 32);               \
            const float val = hi4 == 0 ? v0 : hi4 == 1 ? v1 : hi4 == 2 ? v2 : v3; \
            unsafeAtomicAdd(&aggr[(size_t)d * 64 + lane], val);               \
            r = e2;                                                           \
        }                                                                     \
    }
    SEGREDUCE(0, accA)
    SEGREDUCE(1, accB)
#undef SEGREDUCE
}

// ---------------------------------------------------------------------------
// MFMA combine: h = xin_b16 @ Wr + aggr/deg; zeroes aggr behind the read
// (replaces the inter-layer memset); BN partials.
__global__ __launch_bounds__(256) void k_combine(const unsigned short* __restrict__ xbin,
                                                 const unsigned short* __restrict__ Wrb,
                                                 float* __restrict__ aggr,
                                                 const int*   __restrict__ ihist,
                                                 float* __restrict__ h,
                                                 float* __restrict__ partial) {
    __shared__ float ssum[4][64];
    __shared__ float ssq[4][64];

    const int tid  = threadIdx.x;
    const int lane = tid & 63;
    const int w    = tid >> 6;
    const int wt   = blockIdx.x * 4 + w;
    const int fr   = lane & 15;
    const int hi4  = lane >> 4;
    const int koff = hi4 * 8;
    const int rb   = hi4 * 4;

    float rs[4] = {0.f, 0.f, 0.f, 0.f};
    float rq[4] = {0.f, 0.f, 0.f, 0.f};

    if (wt < NWT) {
        const int n0 = wt * 16;
        const short8 a0 = *(const short8*)(xbin + (size_t)(n0 + fr) * 64 + koff);
        const short8 a1 = *(const short8*)(xbin + (size_t)(n0 + fr) * 64 + 32 + koff);
        f32x4 acc[4] = {};
#pragma unroll
        for (int kb = 0; kb < 2; ++kb) {
            const short8 a = kb == 0 ? a0 : a1;
#pragma unroll
            for (int nn = 0; nn < 4; ++nn) {
                const short8 bh = *(const short8*)(Wrb + (nn * 16 + fr) * 64 + kb * 32 + koff);
                acc[nn] = __builtin_amdgcn_mfma_f32_16x16x32_bf16(a, bh, acc[nn], 0, 0, 0);
            }
        }
        const int4 degs = *(const int4*)(ihist + n0 + rb);
#pragma unroll
        for (int j = 0; j < 4; ++j) {
            const int dg = (&degs.x)[j];
            const float invc = 1.0f / fmaxf((float)dg, 1.0f);
            const int row = n0 + rb + j;
#pragma unroll
            for (int nn = 0; nn < 4; ++nn) {
                const size_t ai = (size_t)row * 64 + nn * 16 + fr;
                const float av = aggr[ai];
                aggr[ai] = 0.f;                       // ready for next layer
                const float v = acc[nn][j] + av * invc;
                h[ai] = v;
                rs[nn] += v;
                rq[nn] += v * v;
            }
        }
    }

#pragma unroll
    for (int nn = 0; nn < 4; ++nn) {
        rs[nn] += __shfl_xor(rs[nn], 16); rs[nn] += __shfl_xor(rs[nn], 32);
        rq[nn] += __shfl_xor(rq[nn], 16); rq[nn] += __shfl_xor(rq[nn], 32);
    }
    if (hi4 == 0) {
#pragma unroll
        for (int nn = 0; nn < 4; ++nn) {
            ssum[w][nn * 16 + fr] = rs[nn];
            ssq[w][nn * 16 + fr]  = rq[nn];
        }
    }
    __syncthreads();
    if (tid < 64) {
        partial[blockIdx.x * 128 + tid] =
            ssum[0][tid] + ssum[1][tid] + ssum[2][tid] + ssum[3][tid];
    } else if (tid < 128) {
        int l = tid - 64;
        partial[blockIdx.x * 128 + 64 + l] =
            ssq[0][l] + ssq[1][l] + ssq[2][l] + ssq[3][l];
    }
}

// ---------------------------------------------------------------------------
__global__ void k_bnfin(const float* __restrict__ partial, const float* __restrict__ g,
                        const float* __restrict__ be, float* __restrict__ ss) {
    __shared__ float tot[128];
    int t = threadIdx.x;
    float s = 0.f;
    for (int b = 0; b < NBC; ++b) s += partial[b * 128 + t];
    tot[t] = s;
    __syncthreads();
    if (t < 64) {
        float mu  = tot[t] * (1.0f / (float)N_NODES);
        float var = tot[64 + t] * (1.0f / (float)N_NODES) - mu * mu;
        float sc  = g[t] * rsqrtf(var + EPS);
        ss[t]      = sc;
        ss[64 + t] = be[t] - mu * sc;
    }
}

// ---------------------------------------------------------------------------
// Fused BN-apply (layer2) + global mean pool partial sums (sorted-run atomics).
__global__ __launch_bounds__(256) void k_bnpool(const float* __restrict__ h,
                                                const float* __restrict__ ss,
                                                const int* __restrict__ batch,
                                                float* __restrict__ gsum) {
    const int lane = threadIdx.x & 63;
    const int wid  = (blockIdx.x * blockDim.x + threadIdx.x) >> 6;
    const int nw   = (gridDim.x * blockDim.x) >> 6;
    const float sc = ss[lane];
    const float sh = ss[64 + lane];
    const int chunk = (N_NODES + nw - 1) / nw;
    const int n0 = wid * chunk;
    const int n1 = min(n0 + chunk, N_NODES);
    int curg = -1;
    float acc = 0.f;
    for (int n = n0; n < n1; ++n) {
        int g = __builtin_amdgcn_readfirstlane(batch[n]);
        if (g != curg) {
            if (curg >= 0) unsafeAtomicAdd(&gsum[curg * 64 + lane], acc);
            curg = g;
            acc = 0.f;
        }
        acc += fmaxf(h[(size_t)n * 64 + lane] * sc + sh, 0.f);
    }
    if (curg >= 0) unsafeAtomicAdd(&gsum[curg * 64 + lane], acc);
}

// ---------------------------------------------------------------------------
__global__ void k_final(const float* __restrict__ gsum, const float* __restrict__ gcnt,
                        const float* __restrict__ Wro, const float* __restrict__ bro,
                        float* __restrict__ out) {
    int g = blockIdx.x;
    int lane = threadIdx.x;
    float v = gsum[g * 64 + lane] / fmaxf(gcnt[g], 1.0f) * Wro[lane];
#pragma unroll
    for (int off = 32; off > 0; off >>= 1) v += __shfl_down(v, off, 64);
    if (lane == 0) out[g] = v + bro[0];
}

// ---------------------------------------------------------------------------
extern "C" void kernel_launch(void* const* d_in, const int* in_sizes, int n_in,
                              void* d_out, int out_size, void* d_ws, size_t ws_size,
                              hipStream_t stream) {
    (void)in_sizes; (void)n_in; (void)out_size; (void)ws_size;
    const float* x    = (const float*)d_in[0];
    const int*   ei   = (const int*)d_in[1];   // [2, E]
    const float* ea   = (const float*)d_in[2];
    const int*   batch= (const int*)d_in[3];
    const float* Wn1  = (const float*)d_in[4];
    const float* bn1  = (const float*)d_in[5];
    const float* Wr1  = (const float*)d_in[6];
    const float* g1   = (const float*)d_in[7];
    const float* be1  = (const float*)d_in[8];
    const float* Wn2  = (const float*)d_in[9];
    const float* bn2  = (const float*)d_in[10];
    const float* Wr2  = (const float*)d_in[11];
    const float* g2   = (const float*)d_in[12];
    const float* be2  = (const float*)d_in[13];
    const float* Wro  = (const float*)d_in[14];
    const float* bro  = (const float*)d_in[15];
    const int* src = ei;
    const int* dst = ei + N_EDGES;

    float* ws = (float*)d_ws;
    // ---- zeroed region: [gsum | aggr | ihist] ----
    float* gsum   = ws;                               // 3200
    float* aggr   = gsum + 3200;                      // N*64
    int*   ihist  = (int*)(aggr + (size_t)N_NODES * 64); // NHPAD
    const size_t zero_floats = 3200 + (size_t)N_NODES * 64 + NHPAD;
    // ---- non-zeroed ----
    float* h      = (float*)(ihist + NHPAD);          // N*64
    float* gcnt   = h + (size_t)N_NODES * 64;         // 64
    float* part1  = gcnt + 64;                        // NBC*128
    float* part2  = part1 + NBC * 128;                // NBC*128
    float* ss1    = part2 + NBC * 128;                // 128
    float* ss2    = ss1 + 128;                        // 128
    unsigned short* Wb1  = (unsigned short*)(ss2 + 128); // 64*104
    unsigned short* Wb2  = Wb1 + 6656;
    unsigned short* Wrb1 = Wb2 + 6656;                // 64*64
    unsigned short* Wrb2 = Wrb1 + 4096;
    int* off     = (int*)(Wrb2 + 4096);               // NHPAD
    int* bsum    = off + NHPAD;                       // 128
    int* bscan   = bsum + 128;                        // 128
    int* bcur    = bscan + 128;                       // 128
    int2* binned = (int2*)(bcur + 128);               // E int2
    int* epk     = (int*)(binned + N_EDGES);          // E int
    int* seid    = epk + N_EDGES;                     // E int
    unsigned short* xb  = (unsigned short*)(seid + N_EDGES);   // N*64
    unsigned short* hb  = xb + (size_t)N_NODES * 64;           // N*64
    unsigned short* eaS = hb + (size_t)N_NODES * 64;           // E*32

    hipMemsetAsync(d_ws, 0, zero_floats * sizeof(float), stream);

    // ---- edge sort by dst: histogram, scan, two-level bin+sort ----
    k_hist<<<512, 256, 0, stream>>>(dst, ihist);
    k_scan1<<<SCAN_B, 512, 0, stream>>>(ihist, off, bsum);
    k_scan2<<<1, 64, 0, stream>>>(bsum, bscan);
    k_scan3<<<SCAN_B, 512, 0, stream>>>(off, bscan, bcur);
    k_bin<<<(N_EDGES + BATCH - 1) / BATCH, 256, 0, stream>>>(src, dst, bcur, binned);
    k_sortb<<<NBKT, 256, 0, stream>>>(binned, off, epk, seid);
    k_prepEAS<<<N_EDGES * 4 / 256, 256, 0, stream>>>(ea, seid, eaS);

    k_prep<<<NPX + 1, 256, 0, stream>>>(x, xb, batch, gcnt,
                                        Wn1, Wn2, Wb1, Wb2, Wr1, Wr2, Wrb1, Wrb2);

    // ---- layer 1 ----
    k_edge<<<N_EDGES / 128, 256, 0, stream>>>(xb, eaS, epk, Wb1, bn1, aggr);
    k_combine<<<NBC, 256, 0, stream>>>(xb, Wrb1, aggr, ihist, h, part1);
    k_bnfin<<<1, 128, 0, stream>>>(part1, g1, be1, ss1);
    k_prepH<<<(N_NODES * 8 + 255) / 256, 256, 0, stream>>>(h, ss1, hb);

    // ---- layer 2 ----
    k_edge<<<N_EDGES / 128, 256, 0, stream>>>(hb, eaS, epk, Wb2, bn2, aggr);
    k_combine<<<NBC, 256, 0, stream>>>(hb, Wrb2, aggr, ihist, h, part2);
    k_bnfin<<<1, 128, 0, stream>>>(part2, g2, be2, ss2);

    // ---- readout (BN-apply fused into pool) ----
    k_bnpool<<<256, 256, 0, stream>>>(h, ss2, batch, gsum);
    k_final<<<NUM_GRAPHS, 64, 0, stream>>>(gsum, gcnt, Wro, bro, (float*)d_out);
}